// Round 6
// baseline (234.350 us; speedup 1.0000x reference)
//
#include <hip/hip_runtime.h>

#define NKEYS 64

typedef float vfloat4 __attribute__((ext_vector_type(4)));

__device__ __forceinline__ float bperm_f(int lane_idx, int src_i) {
    return __int_as_float(__builtin_amdgcn_ds_bpermute(lane_idx << 2, src_i));
}

// out[i] = t[x[i]], t[v] = b[k] iff keys[k] == (float)v, else 0.
// NO __syncthreads anywhere: each wave owns a private 64-entry LDS table copy
// (built via a 6-step bpermute binary search over the sorted keys; only
// lgkmcnt drain needed for wave-local LDS visibility). This keeps the depth-2
// global-load pipeline genuinely in flight — a block-wide barrier would force
// s_waitcnt vmcnt(0) and serialize read/translate/store phases.
// Steady-state loop is branch-uniform (exact-resident grid, uniform sweeps);
// stores are nontemporal so the 134 MB output stream doesn't write-allocate
// and evict the input's Infinity-Cache lines.
__global__ __launch_bounds__(256) void sel_xform_kernel(
    const int4* __restrict__ in,
    const float* __restrict__ b,
    const float* __restrict__ keys,
    float* __restrict__ out,
    int nvec, int ntail, const int* __restrict__ in_tail, float* __restrict__ out_tail)
{
    __shared__ float t[4][NKEYS];    // per-wave private copies: no barrier needed
    const int tid  = threadIdx.x;
    const int lane = tid & 63;
    const int wv   = tid >> 6;

    // Per-lane table entry: lower_bound of (float)lane in sorted keys[0..63].
    const float kv = keys[lane];     // lane l holds keys[l]
    const float bv = b[lane];        // lane l holds b[l]
    const int   kv_i   = __float_as_int(kv);
    const float target = (float)lane;
    int pos = 0;
    #pragma unroll
    for (int s = 32; s >= 1; s >>= 1) {
        const float kc = bperm_f(pos + s - 1, kv_i);   // keys[pos+s-1]
        if (kc < target) pos += s;
    }
    const int posc = (pos > NKEYS - 1) ? (NKEYS - 1) : pos;  // jnp.clip
    const float kmatch = bperm_f(posc, kv_i);
    const float bval   = bperm_f(posc, __float_as_int(bv));
    t[wv][lane] = (kmatch == target) ? bval : 0.0f;          // t[lane]
    __threadfence_block();           // lgkmcnt(0): wave-local LDS visibility

    const float* __restrict__ tw = t[wv];

    int i = blockIdx.x * blockDim.x + tid;
    const int stride = gridDim.x * blockDim.x;

    if (i < nvec) {
        int4 v = in[i];              // prime the pipeline
        for (;;) {
            const int  inext = i + stride;
            const bool more  = inext < nvec;    // wave-uniform given layout
            int4 vn;
            if (more) vn = in[inext];           // next load in flight across
                                                // translate+store of current
            vfloat4 o;
            o.x = ((unsigned)v.x < NKEYS) ? tw[v.x] : 0.0f;
            o.y = ((unsigned)v.y < NKEYS) ? tw[v.y] : 0.0f;
            o.z = ((unsigned)v.z < NKEYS) ? tw[v.z] : 0.0f;
            o.w = ((unsigned)v.w < NKEYS) ? tw[v.w] : 0.0f;
            __builtin_nontemporal_store(o, (vfloat4*)(out + ((long)i << 2)));
            if (!more) break;
            v = vn;
            i = inext;
        }
    }

    // Scalar tail (n % 4 elements): uniform scalar scan, no cross-lane ops.
    if (blockIdx.x == 0 && tid < ntail) {
        const float xf = (float)in_tail[tid];
        float r = 0.0f;
        for (int k = 0; k < NKEYS; ++k) r = (keys[k] == xf) ? b[k] : r;  // keys unique
        out_tail[tid] = r;
    }
}

extern "C" void kernel_launch(void* const* d_in, const int* in_sizes, int n_in,
                              void* d_out, int out_size, void* d_ws, size_t ws_size,
                              hipStream_t stream) {
    const int*   x    = (const int*)d_in[0];     // inputs, int32, [8,4096,1024]
    const float* b    = (const float*)d_in[1];   // per-key bias, [64]
    const float* keys = (const float*)d_in[2];   // sorted unique keys, [64]
    float* out = (float*)d_out;

    const int n     = in_sizes[0];
    const int nvec  = n >> 2;        // int4 / float4 groups
    const int ntail = n & 3;

    // Exactly-resident grid: 2048 blocks x 4 waves = 8192 waves = 256 CU x 32.
    // All blocks live from t=0; grid-stride sweeps are uniform (nvec = 8.4M
    // divides evenly for the reference shape -> branch-free steady state).
    int grid = 2048;
    const int nvec_blocks = (nvec + 255) / 256;
    if (grid > nvec_blocks) grid = nvec_blocks;
    if (grid < 1) grid = 1;          // block 0 must exist for the tail

    sel_xform_kernel<<<grid, 256, 0, stream>>>(
        (const int4*)x, b, keys, out,
        nvec, ntail, x + (nvec << 2), out + (nvec << 2));
}